// Round 6
// baseline (208.250 us; speedup 1.0000x reference)
//
#include <hip/hip_runtime.h>
#include <math.h>

#define B_ 8
#define C_ 80
#define H_ 128
#define W_ 128
#define K_ 100
#define MAXOBJS_ 128
#define NGT_ 256
#define HW_ (H_*W_)
#define CHW_ (C_*H_*W_)
#define TOT_ (B_*CHW_)
#define NBINS_ 4096
#define BCAP_ 4096
#define DCAP_ 128
#define CAPLDS_ 1024
#define DLOC_ 128
#define BLOC_ 768
#define NEGINF_ (-INFINITY)

// ---- ws layout (bytes) ----
#define OFF_MISC    64
#define OFF_LISTCNT 96
#define OFF_BDONE   128
#define OFF_SELDONE 160
#define OFF_THRB    192
#define OFF_CNTA    224
#define OFF_CNTB    256
#define OFF_HIST    512
#define ZERO_BYTES  131584
#define OFF_DEFV    131584
#define OFF_DEFI    135680
#define OFF_BORV    139776
#define OFF_BORI    270848
#define OFF_LIST    401920
#define CAP_REQ     196608ull
#define CAP_MAX     262144ull

__device__ __forceinline__ unsigned skey(float x){
    unsigned u = __float_as_uint(x);
    return (u & 0x80000000u) ? ~u : (u | 0x80000000u);
}

// Parallel threshold finder over LDS hist (suffix-scan; no serial walks)
__device__ __forceinline__ void find_thr(const unsigned* __restrict__ lh,
                                         unsigned* __restrict__ part,
                                         unsigned target,
                                         unsigned* out_thr, unsigned* out_cum){
    int t = threadIdx.x;
    unsigned s = 0;
    #pragma unroll
    for(int k=0;k<16;++k) s += lh[t*16+k];
    part[t] = s;
    __syncthreads();
    for(int off=1; off<256; off<<=1){
        unsigned v = (t+off<256) ? part[t+off] : 0u;
        __syncthreads();
        part[t] += v;
        __syncthreads();
    }
    unsigned nxt = (t<255) ? part[t+1] : 0u;
    if(part[t] >= target && nxt < target){
        unsigned cum = nxt;
        int thr = t*16;
        for(int bin=t*16+15; bin>=t*16; --bin){
            unsigned c = lh[bin];
            if(cum + c >= target){ thr = bin; break; }
            cum += c;
        }
        *out_thr = (unsigned)thr;
        *out_cum = cum;
    }
    __syncthreads();
}

// Same, reading the GLOBAL hist with agent-scope loads (no LDS staging)
__device__ __forceinline__ void find_thr_g(const unsigned* __restrict__ gh,
                                           unsigned* __restrict__ part,
                                           unsigned target,
                                           unsigned* out_thr, unsigned* out_cum){
    int t = threadIdx.x;
    unsigned loc[16]; unsigned s = 0;
    #pragma unroll
    for(int k=0;k<16;++k){
        loc[k] = __hip_atomic_load(&gh[t*16+k], __ATOMIC_RELAXED, __HIP_MEMORY_SCOPE_AGENT);
        s += loc[k];
    }
    part[t] = s;
    __syncthreads();
    for(int off=1; off<256; off<<=1){
        unsigned v = (t+off<256) ? part[t+off] : 0u;
        __syncthreads();
        part[t] += v;
        __syncthreads();
    }
    unsigned nxt = (t<255) ? part[t+1] : 0u;
    if(part[t] >= target && nxt < target){
        unsigned cum = nxt; int thr = t*16; bool fnd = false;
        #pragma unroll
        for(int k=15;k>=0;--k){
            if(!fnd){
                if(cum + loc[k] >= target){ thr = t*16+k; fnd = true; }
                else cum += loc[k];
            }
        }
        *out_thr = (unsigned)thr;
        *out_cum = cum;
    }
    __syncthreads();
}

// Row load: one float4; left/right neighbors via cross-lane shuffle (32-lane groups)
__device__ __forceinline__ void loadrow(const float* __restrict__ P, int y, int xq,
                                        float4& f, float& le, float& re){
    if(y >= 0 && y < H_) f = *(const float4*)(P + y*W_ + xq*4);
    else { f.x = NEGINF_; f.y = NEGINF_; f.z = NEGINF_; f.w = NEGINF_; }
    float l = __shfl_up(f.w, 1, 32);
    float r = __shfl_down(f.x, 1, 32);
    le = (xq==0)  ? NEGINF_ : l;
    re = (xq==31) ? NEGINF_ : r;
}

__device__ __forceinline__ void hmax4v(const float4& f, float le, float re, float h[4]){
    h[0]=fmaxf(fmaxf(le,  f.x), f.y);
    h[1]=fmaxf(fmaxf(f.x, f.y), f.z);
    h[2]=fmaxf(fmaxf(f.y, f.z), f.w);
    h[3]=fmaxf(fmaxf(f.z, f.w), re);
}

// Pass 1: one block per HALF-plane. float4 stencil with shuffle-neighbors,
// per-peak LDS emission, packed u16 LDS histogram, focal negative base.
// Last block of each batch computes the top-K threshold bin (fused k_thresh).
__global__ __launch_bounds__(256) void k_main(const float* __restrict__ hm,
        const float* __restrict__ hmt, unsigned* __restrict__ hist,
        double* __restrict__ accum, unsigned* __restrict__ listcnt,
        int2* __restrict__ list, int capB, unsigned* __restrict__ bdone,
        unsigned* __restrict__ thrbin){
    __shared__ unsigned lhp[NBINS_/2];   // packed u16 pairs
    __shared__ int2 lbuf[CAPLDS_];
    __shared__ unsigned part[256];
    __shared__ float wsum[4];
    __shared__ unsigned lcnt, lbase, thrs, cums;
    __shared__ int amlast;
    int t = threadIdx.x;
    int plane = blockIdx.x >> 1;
    int half  = blockIdx.x & 1;
    int b = plane / C_;
    int cls = plane - b*C_;
    const float* P = hm  + (size_t)plane*HW_;
    const float* T = hmt + (size_t)plane*HW_;
    int idx0 = cls*HW_;

    for(int i=t;i<NBINS_/2;i+=256) lhp[i]=0u;
    if(t==0){ lcnt=0u; thrs=0u; cums=0u; }
    __syncthreads();

    int xq = t & 31;
    int y0 = half*64 + (t>>5)*8;

    float4 vp; float lep, rep;
    loadrow(P, y0-1, xq, vp, lep, rep);
    float hp[4]; hmax4v(vp, lep, rep, hp);
    float4 vc; float lec, rec;
    loadrow(P, y0, xq, vc, lec, rec);

    float acc = 0.f;
    for(int rr=0; rr<8; ++rr){
        int y = y0 + rr;
        float4 vn; float len, ren;
        loadrow(P, y+1, xq, vn, len, ren);
        float hn[4]; hmax4v(vn, len, ren, hn);
        float vv[4]  = {vc.x, vc.y, vc.z, vc.w};
        float lrv[4];
        lrv[0]=fmaxf(lec,  vc.y);
        lrv[1]=fmaxf(vc.x, vc.z);
        lrv[2]=fmaxf(vc.y, vc.w);
        lrv[3]=fmaxf(vc.z, rec);
        float4 tg = *(const float4*)(T + y*W_ + xq*4);
        float tgv[4] = {tg.x, tg.y, tg.z, tg.w};
        #pragma unroll
        for(int j=0;j<4;++j){
            float v = vv[j];
            bool pk = (v>=lrv[j]) && (v>=hp[j]) && (v>=hn[j]);
            if(pk){
                unsigned bin = skey(v)>>20;
                atomicAdd(&lhp[bin>>1], 1u<<((bin&1)<<4));
                if(capB){
                    unsigned p = atomicAdd(&lcnt, 1u);
                    int2 e; e.x = __float_as_int(v); e.y = idx0 + y*W_ + xq*4 + j;
                    if(p < CAPLDS_) lbuf[p] = e;
                    else {
                        unsigned g = atomicAdd(&listcnt[b], 1u);
                        if(g < (unsigned)capB) list[(size_t)b*capB + g] = e;
                    }
                }
            }
            float pr = 1.f/(1.f + __expf(-v));
            pr = fminf(fmaxf(pr, 1e-4f), 1.f - 1e-4f);
            float q = 1.f - tgv[j]; float q2 = q*q;
            acc += __logf(1.f - pr) * pr * pr * q2 * q2;
        }
        #pragma unroll
        for(int j=0;j<4;++j) hp[j] = fmaxf(lrv[j], vv[j]);
        vc = vn; lec = len; rec = ren;
    }
    __syncthreads();

    unsigned n = lcnt; if(n > CAPLDS_) n = CAPLDS_;
    if(capB && t==0) lbase = atomicAdd(&listcnt[b], n);
    for(int i=t;i<NBINS_/2;i+=256){
        unsigned w = lhp[i];
        if(w){
            unsigned c0 = w & 0xFFFFu, c1 = w >> 16;
            if(c0) atomicAdd(&hist[b*NBINS_ + 2*i],     c0);
            if(c1) atomicAdd(&hist[b*NBINS_ + 2*i + 1], c1);
        }
    }
    #pragma unroll
    for(int off=32; off>0; off>>=1) acc += __shfl_xor(acc, off, 64);
    if((t & 63) == 0) wsum[t>>6] = acc;
    __syncthreads();
    if(capB){
        for(unsigned i=t;i<n;i+=256){
            unsigned g = lbase + i;
            if(g < (unsigned)capB) list[(size_t)b*capB + g] = lbuf[i];
        }
    }
    if(t==0) atomicAdd(&accum[0], (double)(wsum[0]+wsum[1]+wsum[2]+wsum[3]));

    // fused per-batch threshold: last of the batch's 160 blocks computes it
    __threadfence();
    __syncthreads();
    if(t==0){
        unsigned d = atomicAdd(&bdone[b], 1u);
        amlast = (d == (unsigned)(2*C_ - 1));
    }
    __syncthreads();
    if(amlast){
        __threadfence();
        find_thr_g(&hist[b*NBINS_], part, (unsigned)K_, &thrs, &cums);
        if(t==0) thrbin[b] = thrs;
    }
}

// Path A: classify peak-list chunks vs thrbin with block-aggregated atomics
__global__ __launch_bounds__(256) void k_scan(const int2* __restrict__ list,
        const unsigned* __restrict__ listcnt, int capB,
        const unsigned* __restrict__ thrbin,
        unsigned* __restrict__ cntA, unsigned* __restrict__ cntB,
        float* __restrict__ defv, int* __restrict__ defi,
        float* __restrict__ borv, int* __restrict__ bori){
    __shared__ int2 dloc[DLOC_];
    __shared__ int2 bloc[BLOC_];
    __shared__ unsigned dc, bc, dbase, bbase;
    int b = blockIdx.x >> 6;
    int chunk = blockIdx.x & 63;
    int t = threadIdx.x;
    if(t==0){ dc=0u; bc=0u; }
    __syncthreads();
    unsigned thr = thrbin[b];
    unsigned n = listcnt[b]; if(n > (unsigned)capB) n = (unsigned)capB;
    for(unsigned i = chunk*256u + t; i < n; i += 64u*256u){
        int2 e = list[(size_t)b*capB + i];
        float v = __int_as_float(e.x);
        unsigned bin = skey(v) >> 20;
        if(bin > thr){
            unsigned p = atomicAdd(&dc, 1u);
            if(p < DLOC_) dloc[p] = e;
            else { unsigned g = atomicAdd(&cntA[b],1u); if(g<DCAP_){ defv[b*DCAP_+g]=v; defi[b*DCAP_+g]=e.y; } }
        } else if(bin == thr){
            unsigned p = atomicAdd(&bc, 1u);
            if(p < BLOC_) bloc[p] = e;
            else { unsigned g = atomicAdd(&cntB[b],1u); if(g<BCAP_){ borv[b*BCAP_+g]=v; bori[b*BCAP_+g]=e.y; } }
        }
    }
    __syncthreads();
    unsigned dn = dc < DLOC_ ? dc : DLOC_;
    unsigned bn = bc < BLOC_ ? bc : BLOC_;
    if(t==0){
        dbase = dn ? atomicAdd(&cntA[b], dn) : 0u;
        bbase = bn ? atomicAdd(&cntB[b], bn) : 0u;
    }
    __syncthreads();
    for(unsigned i=t;i<dn;i+=256){
        unsigned g = dbase + i;
        if(g < DCAP_){ defv[b*DCAP_+g]=__int_as_float(dloc[i].x); defi[b*DCAP_+g]=dloc[i].y; }
    }
    for(unsigned i=t;i<bn;i+=256){
        unsigned g = bbase + i;
        if(g < BCAP_){ borv[b*BCAP_+g]=__int_as_float(bloc[i].x); bori[b*BCAP_+g]=bloc[i].y; }
    }
}

// Path B fallback (small ws): full rescan
__device__ __forceinline__ bool is_peak_scalar(const float* __restrict__ hm, int idx, float v){
    int w = idx & (W_-1);
    int h = (idx >> 7) & (H_-1);
    bool peak = true;
    #pragma unroll
    for(int dy=-1; dy<=1; ++dy){
        int hh = h + dy;
        if(hh < 0 || hh >= H_) continue;
        #pragma unroll
        for(int dx=-1; dx<=1; ++dx){
            if(dy==0 && dx==0) continue;
            int ww = w + dx;
            if(ww < 0 || ww >= W_) continue;
            peak = peak && (v >= __ldg(&hm[idx + dy*W_ + dx]));
        }
    }
    return peak;
}

__global__ __launch_bounds__(256) void k_collect(const float* __restrict__ hm,
        const unsigned* __restrict__ thrbin,
        unsigned* __restrict__ cntA, unsigned* __restrict__ cntB,
        float* __restrict__ defv, int* __restrict__ defi,
        float* __restrict__ borv, int* __restrict__ bori){
    int idx = blockIdx.x*256 + threadIdx.x;
    float v = hm[idx];
    if(!is_peak_scalar(hm, idx, v)) return;
    int b = idx / CHW_;
    unsigned bin = skey(v) >> 20;
    unsigned thr = thrbin[b];
    if(bin > thr){
        unsigned p = atomicAdd(&cntA[b], 1u);
        if(p < DCAP_){ defv[b*DCAP_+p] = v; defi[b*DCAP_+p] = idx - b*CHW_; }
    } else if(bin == thr){
        unsigned p = atomicAdd(&cntB[b], 1u);
        if(p < BCAP_){ borv[b*BCAP_+p] = v; bori[b*BCAP_+p] = idx - b*CHW_; }
    }
}

// Per-batch: radix-refine top-K, decode boxes, pair-parallel IoU vs batch GT,
// focal fixup. Last finishing block does the L1 heads + final combine (fused).
__global__ __launch_bounds__(256) void k_select(const float* __restrict__ hm,
        const float* __restrict__ hmt, const float* __restrict__ wh,
        const float* __restrict__ reg, const float* __restrict__ tbox,
        const int* __restrict__ tbid,
        const float* __restrict__ wht, const float* __restrict__ regt,
        const int* __restrict__ mask, const int* __restrict__ ind,
        const unsigned* __restrict__ cntA, const unsigned* __restrict__ cntB,
        const float* __restrict__ defv, const int* __restrict__ defi,
        const float* __restrict__ borv, const int* __restrict__ bori,
        double* __restrict__ accum, int* __restrict__ misc,
        unsigned* __restrict__ seldone, float* __restrict__ out){
    int b = blockIdx.x, t = threadIdx.x;
    __shared__ float gbox[NGT_][4];
    __shared__ float garea[NGT_];
    __shared__ float sv[BCAP_];
    __shared__ int   si[BCAP_];
    __shared__ unsigned h2[NBINS_];
    __shared__ unsigned t4[BCAP_];
    __shared__ unsigned part[256];
    __shared__ int  rvI[256];
    __shared__ int  sel[K_];
    __shared__ float sbx[K_][4];
    __shared__ float sa[K_];
    __shared__ int   ioui[K_];
    __shared__ float r0s[256], r1s[256], r2s[256];
    __shared__ unsigned gcnt, selc, t3c, t4c;
    __shared__ unsigned thr2s, cum2s, thr3s, need3s;
    __shared__ int wsel, amlast;

    int nA = (int)cntA[b]; if(nA>DCAP_) nA=DCAP_; if(nA>K_) nA=K_;
    int nB = (int)cntB[b]; if(nB>BCAP_) nB=BCAP_;
    int m = K_ - nA; if(m>nB) m=nB; if(m<0) m=0;

    if(t==0){ gcnt=0u; selc=(unsigned)nA; t3c=0u; t4c=0u;
              thr2s=0u; cum2s=0u; thr3s=0u; need3s=0u; }
    for(int i=t;i<NBINS_;i+=256) h2[i]=0u;
    __syncthreads();

    // stage only this batch's GT boxes (order-free; reduced by max)
    for(int i=t;i<NGT_;i+=256){
        if(tbid[i]==b){
            unsigned p = atomicAdd(&gcnt, 1u);
            float gx1=tbox[i*4+0], gy1=tbox[i*4+1], gx2=tbox[i*4+2], gy2=tbox[i*4+3];
            gbox[p][0]=gx1; gbox[p][1]=gy1; gbox[p][2]=gx2; gbox[p][3]=gy2;
            garea[p]=fmaxf(gx2-gx1,0.f)*fmaxf(gy2-gy1,0.f);
        }
    }
    for(int i=t;i<nB;i+=256){ sv[i]=borv[b*BCAP_+i]; si[i]=bori[b*BCAP_+i]; }
    for(int i=t;i<nA;i+=256) sel[i]=defi[b*DCAP_+i];
    __syncthreads();

    if(m>0){
        for(int i=t;i<nB;i+=256) atomicAdd(&h2[(skey(sv[i])>>8)&0xFFFu], 1u);
        __syncthreads();
        find_thr(h2, part, (unsigned)m, &thr2s, &cum2s);
        unsigned thr2 = thr2s, need2 = (unsigned)m - cum2s;
        for(int i=t;i<nB;i+=256){
            unsigned sb=(skey(sv[i])>>8)&0xFFFu;
            if(sb>thr2){ unsigned p=atomicAdd(&selc,1u); if(p<K_) sel[p]=si[i]; }
            else if(sb==thr2){ unsigned p=atomicAdd(&t3c,1u); if(p<BCAP_) t4[p]=(unsigned)i; }
        }
        __syncthreads();
        unsigned nt3=t3c; if(nt3>BCAP_) nt3=BCAP_;
        part[t]=0u;
        __syncthreads();
        for(unsigned i=t;i<nt3;i+=256) atomicAdd(&part[skey(sv[t4[i]])&0xFFu], 1u);
        __syncthreads();
        for(int off=1; off<256; off<<=1){
            unsigned v = (t+off<256)? part[t+off] : 0u;
            __syncthreads();
            part[t] += v;
            __syncthreads();
        }
        {
            unsigned nxt = (t<255)? part[t+1] : 0u;
            if(part[t] >= need2 && nxt < need2){ thr3s=(unsigned)t; need3s=need2-nxt; }
        }
        __syncthreads();
        unsigned thr3=thr3s, need3=need3s;
        for(unsigned i=t;i<nt3;i+=256){
            unsigned ci=t4[i];
            unsigned lb=skey(sv[ci])&0xFFu;
            if(lb>thr3){ unsigned p=atomicAdd(&selc,1u); if(p<K_) sel[p]=si[ci]; }
            else if(lb==thr3){ unsigned p=atomicAdd(&t4c,1u); if(p<NBINS_) h2[p]=(unsigned)si[ci]; }
        }
        __syncthreads();
        unsigned n4=t4c; if(n4>NBINS_) n4=NBINS_;
        if(need3 >= n4){
            for(unsigned i=t;i<n4;i+=256){ unsigned p=atomicAdd(&selc,1u); if(p<K_) sel[p]=(int)h2[i]; }
            __syncthreads();
        } else {
            for(unsigned it=0; it<need3; ++it){
                int bi=0x7FFFFFFF;
                for(unsigned i=t;i<n4;i+=256){ int w=(int)h2[i]; bi = (w<bi)?w:bi; }
                rvI[t]=bi;
                __syncthreads();
                for(int st=128;st>0;st>>=1){
                    if(t<st){ int w=rvI[t+st]; if(w<rvI[t]) rvI[t]=w; }
                    __syncthreads();
                }
                if(t==0){ wsel=rvI[0]; unsigned p=selc; selc=p+1u; if(p<K_) sel[p]=wsel; }
                __syncthreads();
                int w=wsel;
                for(unsigned i=t;i<n4;i+=256) if((int)h2[i]==w) h2[i]=0x7FFFFFFFu;
                __syncthreads();
            }
        }
    }
    __syncthreads();

    int nsel=(int)selc; if(nsel>K_) nsel=K_;
    // decode boxes
    for(int k=t;k<nsel;k+=256){
        int idx = sel[k];
        int cls = idx / HW_;
        int sp  = idx - cls*HW_;
        int yi = sp>>7, xi = sp&(W_-1);
        float rr0 = reg[(b*2+0)*HW_+sp], rr1 = reg[(b*2+1)*HW_+sp];
        float w0 = wh[(b*2+0)*HW_+sp],  w1 = wh[(b*2+1)*HW_+sp];
        float xs = (float)xi + rr0, ys = (float)yi + rr1;
        float x1=xs-w0*0.5f, y1=ys-w1*0.5f, x2=xs+w0*0.5f, y2=ys+w1*0.5f;
        sbx[k][0]=x1; sbx[k][1]=y1; sbx[k][2]=x2; sbx[k][3]=y2;
        sa[k] = fmaxf(x2-x1,0.f)*fmaxf(y2-y1,0.f);
        ioui[k] = 0;
    }
    __syncthreads();
    // pair-parallel IoU, max via LDS atomicMax (float bits, non-negative)
    int ng = (int)gcnt; if(ng>NGT_) ng=NGT_;
    for(int pi=t; pi<nsel*ng; pi+=256){
        int k = pi / ng, g = pi - k*ng;
        float x1=sbx[k][0], y1=sbx[k][1], x2=sbx[k][2], y2=sbx[k][3];
        float ix1=fmaxf(x1,gbox[g][0]), iy1=fmaxf(y1,gbox[g][1]);
        float ix2=fminf(x2,gbox[g][2]), iy2=fminf(y2,gbox[g][3]);
        float iw=fmaxf(ix2-ix1,0.f), ih=fmaxf(iy2-iy1,0.f);
        float inter=iw*ih;
        float uni = sa[k] + garea[g] - inter;
        float iou = inter / fmaxf(uni, 1e-7f);
        atomicMax(&ioui[k], __float_as_int(iou));
    }
    __syncthreads();
    // focal fixup at scattered positions
    for(int k=t;k<nsel;k+=256){
        float best = __int_as_float(ioui[k]);
        int gidx = b*CHW_ + sel[k];
        float v = hm[gidx];
        float p = 1.f/(1.f + __expf(-v));
        p = fminf(fmaxf(p, 1e-4f), 1.f - 1e-4f);
        float gt0 = hmt[gidx];
        float q0 = 1.f - gt0; float q02 = q0*q0;
        float neg0 = __logf(1.f - p) * p * p * q02 * q02;
        float gt1 = fminf(gt0 + 0.1f*best, 1.f);
        if(gt1 == 1.f){
            atomicAdd(&misc[0], 1);
            float op = 1.f - p;
            atomicAdd(&accum[1], (double)(__logf(p)*op*op));
            atomicAdd(&accum[2], (double)(-neg0));
        } else {
            float q1 = 1.f - gt1; float q12 = q1*q1;
            float neg1 = __logf(1.f - p) * p * p * q12 * q12;
            atomicAdd(&accum[2], (double)(neg1 - neg0));
        }
    }

    // fused final: last finishing block does L1 heads + combine
    __threadfence();
    __syncthreads();
    if(t==0){
        unsigned d = atomicAdd(seldone, 1u);
        amlast = (d == (unsigned)(B_-1));
    }
    __syncthreads();
    if(amlast){
        __threadfence();
        float whn=0.f, offn=0.f, ms=0.f;
        for(int i=t;i<B_*MAXOBJS_;i+=256){
            int bb = i >> 7;
            float mk = (float)mask[i];
            int id = ind[i];
            float p0 = wh[(bb*2+0)*HW_+id], p1 = wh[(bb*2+1)*HW_+id];
            whn += mk*(fabsf(p0 - wht[2*i]) + fabsf(p1 - wht[2*i+1]));
            float q0 = reg[(bb*2+0)*HW_+id], q1 = reg[(bb*2+1)*HW_+id];
            offn += mk*(fabsf(q0 - regt[2*i]) + fabsf(q1 - regt[2*i+1]));
            ms += 2.f*mk;
        }
        r0s[t]=whn; r1s[t]=offn; r2s[t]=ms;
        __syncthreads();
        for(int st=128; st>0; st>>=1){
            if(t<st){ r0s[t]+=r0s[t+st]; r1s[t]+=r1s[t+st]; r2s[t]+=r2s[t+st]; }
            __syncthreads();
        }
        if(t==0){
            double nb  = __hip_atomic_load(&accum[0], __ATOMIC_RELAXED, __HIP_MEMORY_SCOPE_AGENT);
            double pos = __hip_atomic_load(&accum[1], __ATOMIC_RELAXED, __HIP_MEMORY_SCOPE_AGENT);
            double nd  = __hip_atomic_load(&accum[2], __ATOMIC_RELAXED, __HIP_MEMORY_SCOPE_AGENT);
            int np = __hip_atomic_load(&misc[0], __ATOMIC_RELAXED, __HIP_MEMORY_SCOPE_AGENT);
            double neg = nb + nd;
            float hm_loss = (np > 0) ? (float)(-(pos + neg)/(double)np) : (float)(-neg);
            float msum = r2s[0];
            float wh_loss  = r0s[0] / (msum + 1e-4f);
            float off_loss = r1s[0] / (msum + 1e-4f);
            out[0] = hm_loss + 0.1f*wh_loss + off_loss;
            out[1] = hm_loss; out[2] = wh_loss; out[3] = off_loss;
        }
    }
}

extern "C" void kernel_launch(void* const* d_in, const int* in_sizes, int n_in,
                              void* d_out, int out_size, void* d_ws, size_t ws_size,
                              hipStream_t stream){
    const float* hm   = (const float*)d_in[0];
    const float* wh   = (const float*)d_in[1];
    const float* reg  = (const float*)d_in[2];
    const float* hmt  = (const float*)d_in[3];
    const float* wht  = (const float*)d_in[4];
    const float* regt = (const float*)d_in[5];
    const int*   mask = (const int*)d_in[6];
    const int*   ind  = (const int*)d_in[7];
    const float* tbox = (const float*)d_in[8];
    const int*   tbid = (const int*)d_in[9];

    char* ws = (char*)d_ws;
    double*   accum   = (double*)ws;
    int*      misc    = (int*)(ws + OFF_MISC);
    unsigned* listcnt = (unsigned*)(ws + OFF_LISTCNT);
    unsigned* bdone   = (unsigned*)(ws + OFF_BDONE);
    unsigned* seldone = (unsigned*)(ws + OFF_SELDONE);
    unsigned* thrbin  = (unsigned*)(ws + OFF_THRB);
    unsigned* cntA    = (unsigned*)(ws + OFF_CNTA);
    unsigned* cntB    = (unsigned*)(ws + OFF_CNTB);
    unsigned* hist    = (unsigned*)(ws + OFF_HIST);
    float*    defv    = (float*)(ws + OFF_DEFV);
    int*      defi    = (int*)(ws + OFF_DEFI);
    float*    borv    = (float*)(ws + OFF_BORV);
    int*      bori    = (int*)(ws + OFF_BORI);
    int2*     list    = (int2*)(ws + OFF_LIST);

    size_t capB = 0;
    if(ws_size >= (size_t)OFF_LIST + CAP_REQ*(size_t)B_*8ull){
        capB = (ws_size - (size_t)OFF_LIST) / ((size_t)B_*8ull);
        if(capB > CAP_MAX) capB = CAP_MAX;
    }

    hipMemsetAsync(ws, 0, ZERO_BYTES, stream);
    k_main<<<B_*C_*2, 256, 0, stream>>>(hm, hmt, hist, accum, listcnt, list,
                                        (int)capB, bdone, thrbin);
    if(capB){
        k_scan<<<B_*64, 256, 0, stream>>>(list, listcnt, (int)capB, thrbin,
                                          cntA, cntB, defv, defi, borv, bori);
    } else {
        k_collect<<<TOT_/256, 256, 0, stream>>>(hm, thrbin, cntA, cntB,
                                                defv, defi, borv, bori);
    }
    k_select<<<B_, 256, 0, stream>>>(hm, hmt, wh, reg, tbox, tbid,
                                     wht, regt, mask, ind, cntA, cntB,
                                     defv, defi, borv, bori, accum, misc,
                                     seldone, (float*)d_out);
    (void)in_sizes; (void)n_in; (void)out_size;
}

// Round 7
// 81.413 us; speedup vs baseline: 2.5579x; 2.5579x over previous
//
#include <hip/hip_runtime.h>
#include <math.h>

#define B_ 8
#define C_ 80
#define H_ 128
#define W_ 128
#define K_ 100
#define MAXOBJS_ 128
#define NGT_ 256
#define HW_ (H_*W_)
#define CHW_ (C_*H_*W_)
#define TOT_ (B_*CHW_)
#define NBINS_ 4096
#define BCAP_ 4096
#define DCAP_ 128
#define CAPLDS_ 1024
#define DLOC_ 128
#define BLOC_ 768
#define NEGINF_ (-INFINITY)

// ---- ws layout (bytes) ----
#define OFF_MISC    64
#define OFF_LISTCNT 96
#define OFF_BDONE   128
#define OFF_SELDONE 160
#define OFF_THRB    192
#define OFF_CNTA    224
#define OFF_CNTB    256
#define OFF_HIST    512
#define ZERO_BYTES  131584
#define OFF_DEFV    131584
#define OFF_DEFI    135680
#define OFF_BORV    139776
#define OFF_BORI    270848
#define OFF_LIST    401920
#define CAP_REQ     196608ull
#define CAP_MAX     262144ull

__device__ __forceinline__ unsigned skey(float x){
    unsigned u = __float_as_uint(x);
    return (u & 0x80000000u) ? ~u : (u | 0x80000000u);
}

// Parallel threshold finder over LDS hist (suffix-scan; no serial walks)
__device__ __forceinline__ void find_thr(const unsigned* __restrict__ lh,
                                         unsigned* __restrict__ part,
                                         unsigned target,
                                         unsigned* out_thr, unsigned* out_cum){
    int t = threadIdx.x;
    unsigned s = 0;
    #pragma unroll
    for(int k=0;k<16;++k) s += lh[t*16+k];
    part[t] = s;
    __syncthreads();
    for(int off=1; off<256; off<<=1){
        unsigned v = (t+off<256) ? part[t+off] : 0u;
        __syncthreads();
        part[t] += v;
        __syncthreads();
    }
    unsigned nxt = (t<255) ? part[t+1] : 0u;
    if(part[t] >= target && nxt < target){
        unsigned cum = nxt;
        int thr = t*16;
        for(int bin=t*16+15; bin>=t*16; --bin){
            unsigned c = lh[bin];
            if(cum + c >= target){ thr = bin; break; }
            cum += c;
        }
        *out_thr = (unsigned)thr;
        *out_cum = cum;
    }
    __syncthreads();
}

__device__ __forceinline__ void hmax4v(const float4& f, float le, float re, float h[4]){
    h[0]=fmaxf(fmaxf(le,  f.x), f.y);
    h[1]=fmaxf(fmaxf(f.x, f.y), f.z);
    h[2]=fmaxf(fmaxf(f.y, f.z), f.w);
    h[3]=fmaxf(fmaxf(f.z, f.w), re);
}

// Pass 1: one block per HALF-plane. Each thread BATCH-LOADS its 10 hm rows and
// 8 hmt rows into registers (18 independent float4 loads in flight -> full MLP,
// no per-row waits), then shuffles neighbors, then computes peaks + focal base.
__global__ __launch_bounds__(256) void k_main(const float* __restrict__ hm,
        const float* __restrict__ hmt, unsigned* __restrict__ hist,
        double* __restrict__ accum, unsigned* __restrict__ listcnt,
        int2* __restrict__ list, int capB){
    __shared__ unsigned lh[NBINS_];
    __shared__ int2 lbuf[CAPLDS_];
    __shared__ float wsum[4];
    __shared__ unsigned lcnt, lbase;
    int t = threadIdx.x;
    int plane = blockIdx.x >> 1;
    int half  = blockIdx.x & 1;
    int b = plane / C_;
    int cls = plane - b*C_;
    const float* P = hm  + (size_t)plane*HW_;
    const float* T = hmt + (size_t)plane*HW_;
    int idx0 = cls*HW_;

    for(int i=t;i<NBINS_;i+=256) lh[i]=0u;
    if(t==0) lcnt=0u;
    __syncthreads();

    int xq = t & 31;
    int y0 = half*64 + (t>>5)*8;

    // ---- batch loads: 10 hm rows (y0-1 .. y0+8), 8 hmt rows ----
    float4 rows[10];
    #pragma unroll
    for(int r=0;r<10;++r){
        int y = y0 - 1 + r;
        if(y >= 0 && y < H_) rows[r] = *(const float4*)(P + y*W_ + xq*4);
        else { rows[r].x=NEGINF_; rows[r].y=NEGINF_; rows[r].z=NEGINF_; rows[r].w=NEGINF_; }
    }
    float4 tgt[8];
    #pragma unroll
    for(int r=0;r<8;++r) tgt[r] = *(const float4*)(T + (y0+r)*W_ + xq*4);

    // ---- neighbor columns via shuffles (data already resident) ----
    float le[10], re[10];
    #pragma unroll
    for(int r=0;r<10;++r){
        float l  = __shfl_up(rows[r].w, 1, 32);
        float rr = __shfl_down(rows[r].x, 1, 32);
        le[r] = (xq==0)  ? NEGINF_ : l;
        re[r] = (xq==31) ? NEGINF_ : rr;
    }

    // ---- compute ----
    float acc = 0.f;
    #pragma unroll
    for(int ri=0; ri<8; ++ri){
        int r = ri + 1;
        int y = y0 + ri;
        float vv[4] = {rows[r].x, rows[r].y, rows[r].z, rows[r].w};
        float hp[4]; hmax4v(rows[r-1], le[r-1], re[r-1], hp);
        float hn[4]; hmax4v(rows[r+1], le[r+1], re[r+1], hn);
        float lrv[4];
        lrv[0]=fmaxf(le[r], vv[1]);
        lrv[1]=fmaxf(vv[0], vv[2]);
        lrv[2]=fmaxf(vv[1], vv[3]);
        lrv[3]=fmaxf(vv[2], re[r]);
        float tgv[4] = {tgt[ri].x, tgt[ri].y, tgt[ri].z, tgt[ri].w};
        #pragma unroll
        for(int j=0;j<4;++j){
            float v = vv[j];
            bool pk = (v>=lrv[j]) && (v>=hp[j]) && (v>=hn[j]);
            if(pk){
                atomicAdd(&lh[skey(v)>>20], 1u);
                if(capB){
                    unsigned p = atomicAdd(&lcnt, 1u);
                    int2 e; e.x = __float_as_int(v); e.y = idx0 + y*W_ + xq*4 + j;
                    if(p < CAPLDS_) lbuf[p] = e;
                    else {
                        unsigned g = atomicAdd(&listcnt[b], 1u);
                        if(g < (unsigned)capB) list[(size_t)b*capB + g] = e;
                    }
                }
            }
            float pr = 1.f/(1.f + __expf(-v));
            pr = fminf(fmaxf(pr, 1e-4f), 1.f - 1e-4f);
            float q = 1.f - tgv[j]; float q2 = q*q;
            acc += __logf(1.f - pr) * pr * pr * q2 * q2;
        }
    }
    __syncthreads();

    unsigned n = lcnt; if(n > CAPLDS_) n = CAPLDS_;
    if(capB && t==0) lbase = atomicAdd(&listcnt[b], n);
    for(int i=t;i<NBINS_;i+=256){ unsigned c=lh[i]; if(c) atomicAdd(&hist[b*NBINS_+i], c); }
    #pragma unroll
    for(int off=32; off>0; off>>=1) acc += __shfl_xor(acc, off, 64);
    if((t & 63) == 0) wsum[t>>6] = acc;
    __syncthreads();
    if(capB){
        for(unsigned i=t;i<n;i+=256){
            unsigned g = lbase + i;
            if(g < (unsigned)capB) list[(size_t)b*capB + g] = lbuf[i];
        }
    }
    if(t==0) atomicAdd(&accum[0], (double)(wsum[0]+wsum[1]+wsum[2]+wsum[3]));
}

// Per-batch threshold bin (tiny, fully parallel)
__global__ void k_thresh(const unsigned* __restrict__ hist, unsigned* __restrict__ thrbin){
    __shared__ unsigned lh[NBINS_];
    __shared__ unsigned part[256];
    __shared__ unsigned thrs, cums;
    int b = blockIdx.x, t = threadIdx.x;
    for(int i=t;i<NBINS_;i+=256) lh[i]=hist[b*NBINS_+i];
    if(t==0){ thrs=0u; cums=0u; }
    __syncthreads();
    find_thr(lh, part, (unsigned)K_, &thrs, &cums);
    if(t==0) thrbin[b]=thrs;
}

// Path A: classify peak-list chunks vs thrbin with block-aggregated atomics
__global__ __launch_bounds__(256) void k_scan(const int2* __restrict__ list,
        const unsigned* __restrict__ listcnt, int capB,
        const unsigned* __restrict__ thrbin,
        unsigned* __restrict__ cntA, unsigned* __restrict__ cntB,
        float* __restrict__ defv, int* __restrict__ defi,
        float* __restrict__ borv, int* __restrict__ bori){
    __shared__ int2 dloc[DLOC_];
    __shared__ int2 bloc[BLOC_];
    __shared__ unsigned dc, bc, dbase, bbase;
    int b = blockIdx.x >> 6;
    int chunk = blockIdx.x & 63;
    int t = threadIdx.x;
    if(t==0){ dc=0u; bc=0u; }
    __syncthreads();
    unsigned thr = thrbin[b];
    unsigned n = listcnt[b]; if(n > (unsigned)capB) n = (unsigned)capB;
    for(unsigned i = chunk*256u + t; i < n; i += 64u*256u){
        int2 e = list[(size_t)b*capB + i];
        float v = __int_as_float(e.x);
        unsigned bin = skey(v) >> 20;
        if(bin > thr){
            unsigned p = atomicAdd(&dc, 1u);
            if(p < DLOC_) dloc[p] = e;
            else { unsigned g = atomicAdd(&cntA[b],1u); if(g<DCAP_){ defv[b*DCAP_+g]=v; defi[b*DCAP_+g]=e.y; } }
        } else if(bin == thr){
            unsigned p = atomicAdd(&bc, 1u);
            if(p < BLOC_) bloc[p] = e;
            else { unsigned g = atomicAdd(&cntB[b],1u); if(g<BCAP_){ borv[b*BCAP_+g]=v; bori[b*BCAP_+g]=e.y; } }
        }
    }
    __syncthreads();
    unsigned dn = dc < DLOC_ ? dc : DLOC_;
    unsigned bn = bc < BLOC_ ? bc : BLOC_;
    if(t==0){
        dbase = dn ? atomicAdd(&cntA[b], dn) : 0u;
        bbase = bn ? atomicAdd(&cntB[b], bn) : 0u;
    }
    __syncthreads();
    for(unsigned i=t;i<dn;i+=256){
        unsigned g = dbase + i;
        if(g < DCAP_){ defv[b*DCAP_+g]=__int_as_float(dloc[i].x); defi[b*DCAP_+g]=dloc[i].y; }
    }
    for(unsigned i=t;i<bn;i+=256){
        unsigned g = bbase + i;
        if(g < BCAP_){ borv[b*BCAP_+g]=__int_as_float(bloc[i].x); bori[b*BCAP_+g]=bloc[i].y; }
    }
}

// Path B fallback (small ws): full rescan
__device__ __forceinline__ bool is_peak_scalar(const float* __restrict__ hm, int idx, float v){
    int w = idx & (W_-1);
    int h = (idx >> 7) & (H_-1);
    bool peak = true;
    #pragma unroll
    for(int dy=-1; dy<=1; ++dy){
        int hh = h + dy;
        if(hh < 0 || hh >= H_) continue;
        #pragma unroll
        for(int dx=-1; dx<=1; ++dx){
            if(dy==0 && dx==0) continue;
            int ww = w + dx;
            if(ww < 0 || ww >= W_) continue;
            peak = peak && (v >= __ldg(&hm[idx + dy*W_ + dx]));
        }
    }
    return peak;
}

__global__ __launch_bounds__(256) void k_collect(const float* __restrict__ hm,
        const unsigned* __restrict__ thrbin,
        unsigned* __restrict__ cntA, unsigned* __restrict__ cntB,
        float* __restrict__ defv, int* __restrict__ defi,
        float* __restrict__ borv, int* __restrict__ bori){
    int idx = blockIdx.x*256 + threadIdx.x;
    float v = hm[idx];
    if(!is_peak_scalar(hm, idx, v)) return;
    int b = idx / CHW_;
    unsigned bin = skey(v) >> 20;
    unsigned thr = thrbin[b];
    if(bin > thr){
        unsigned p = atomicAdd(&cntA[b], 1u);
        if(p < DCAP_){ defv[b*DCAP_+p] = v; defi[b*DCAP_+p] = idx - b*CHW_; }
    } else if(bin == thr){
        unsigned p = atomicAdd(&cntB[b], 1u);
        if(p < BCAP_){ borv[b*BCAP_+p] = v; bori[b*BCAP_+p] = idx - b*CHW_; }
    }
}

// Per-batch: radix-refine top-K, decode boxes, pair-parallel IoU vs batch GT,
// focal fixup. Last finishing block does the L1 heads + final combine (fused).
__global__ __launch_bounds__(256) void k_select(const float* __restrict__ hm,
        const float* __restrict__ hmt, const float* __restrict__ wh,
        const float* __restrict__ reg, const float* __restrict__ tbox,
        const int* __restrict__ tbid,
        const float* __restrict__ wht, const float* __restrict__ regt,
        const int* __restrict__ mask, const int* __restrict__ ind,
        const unsigned* __restrict__ cntA, const unsigned* __restrict__ cntB,
        const float* __restrict__ defv, const int* __restrict__ defi,
        const float* __restrict__ borv, const int* __restrict__ bori,
        double* __restrict__ accum, int* __restrict__ misc,
        unsigned* __restrict__ seldone, float* __restrict__ out){
    int b = blockIdx.x, t = threadIdx.x;
    __shared__ float gbox[NGT_][4];
    __shared__ float garea[NGT_];
    __shared__ float sv[BCAP_];
    __shared__ int   si[BCAP_];
    __shared__ unsigned h2[NBINS_];
    __shared__ unsigned t4[BCAP_];
    __shared__ unsigned part[256];
    __shared__ int  rvI[256];
    __shared__ int  sel[K_];
    __shared__ float sbx[K_][4];
    __shared__ float sa[K_];
    __shared__ int   ioui[K_];
    __shared__ float r0s[256], r1s[256], r2s[256];
    __shared__ unsigned gcnt, selc, t3c, t4c;
    __shared__ unsigned thr2s, cum2s, thr3s, need3s;
    __shared__ int wsel, amlast;

    int nA = (int)cntA[b]; if(nA>DCAP_) nA=DCAP_; if(nA>K_) nA=K_;
    int nB = (int)cntB[b]; if(nB>BCAP_) nB=BCAP_;
    int m = K_ - nA; if(m>nB) m=nB; if(m<0) m=0;

    if(t==0){ gcnt=0u; selc=(unsigned)nA; t3c=0u; t4c=0u;
              thr2s=0u; cum2s=0u; thr3s=0u; need3s=0u; }
    for(int i=t;i<NBINS_;i+=256) h2[i]=0u;
    __syncthreads();

    for(int i=t;i<NGT_;i+=256){
        if(tbid[i]==b){
            unsigned p = atomicAdd(&gcnt, 1u);
            float gx1=tbox[i*4+0], gy1=tbox[i*4+1], gx2=tbox[i*4+2], gy2=tbox[i*4+3];
            gbox[p][0]=gx1; gbox[p][1]=gy1; gbox[p][2]=gx2; gbox[p][3]=gy2;
            garea[p]=fmaxf(gx2-gx1,0.f)*fmaxf(gy2-gy1,0.f);
        }
    }
    for(int i=t;i<nB;i+=256){ sv[i]=borv[b*BCAP_+i]; si[i]=bori[b*BCAP_+i]; }
    for(int i=t;i<nA;i+=256) sel[i]=defi[b*DCAP_+i];
    __syncthreads();

    if(m>0){
        for(int i=t;i<nB;i+=256) atomicAdd(&h2[(skey(sv[i])>>8)&0xFFFu], 1u);
        __syncthreads();
        find_thr(h2, part, (unsigned)m, &thr2s, &cum2s);
        unsigned thr2 = thr2s, need2 = (unsigned)m - cum2s;
        for(int i=t;i<nB;i+=256){
            unsigned sb=(skey(sv[i])>>8)&0xFFFu;
            if(sb>thr2){ unsigned p=atomicAdd(&selc,1u); if(p<K_) sel[p]=si[i]; }
            else if(sb==thr2){ unsigned p=atomicAdd(&t3c,1u); if(p<BCAP_) t4[p]=(unsigned)i; }
        }
        __syncthreads();
        unsigned nt3=t3c; if(nt3>BCAP_) nt3=BCAP_;
        part[t]=0u;
        __syncthreads();
        for(unsigned i=t;i<nt3;i+=256) atomicAdd(&part[skey(sv[t4[i]])&0xFFu], 1u);
        __syncthreads();
        for(int off=1; off<256; off<<=1){
            unsigned v = (t+off<256)? part[t+off] : 0u;
            __syncthreads();
            part[t] += v;
            __syncthreads();
        }
        {
            unsigned nxt = (t<255)? part[t+1] : 0u;
            if(part[t] >= need2 && nxt < need2){ thr3s=(unsigned)t; need3s=need2-nxt; }
        }
        __syncthreads();
        unsigned thr3=thr3s, need3=need3s;
        for(unsigned i=t;i<nt3;i+=256){
            unsigned ci=t4[i];
            unsigned lb=skey(sv[ci])&0xFFu;
            if(lb>thr3){ unsigned p=atomicAdd(&selc,1u); if(p<K_) sel[p]=si[ci]; }
            else if(lb==thr3){ unsigned p=atomicAdd(&t4c,1u); if(p<NBINS_) h2[p]=(unsigned)si[ci]; }
        }
        __syncthreads();
        unsigned n4=t4c; if(n4>NBINS_) n4=NBINS_;
        if(need3 >= n4){
            for(unsigned i=t;i<n4;i+=256){ unsigned p=atomicAdd(&selc,1u); if(p<K_) sel[p]=(int)h2[i]; }
            __syncthreads();
        } else {
            for(unsigned it=0; it<need3; ++it){
                int bi=0x7FFFFFFF;
                for(unsigned i=t;i<n4;i+=256){ int w=(int)h2[i]; bi = (w<bi)?w:bi; }
                rvI[t]=bi;
                __syncthreads();
                for(int st=128;st>0;st>>=1){
                    if(t<st){ int w=rvI[t+st]; if(w<rvI[t]) rvI[t]=w; }
                    __syncthreads();
                }
                if(t==0){ wsel=rvI[0]; unsigned p=selc; selc=p+1u; if(p<K_) sel[p]=wsel; }
                __syncthreads();
                int w=wsel;
                for(unsigned i=t;i<n4;i+=256) if((int)h2[i]==w) h2[i]=0x7FFFFFFFu;
                __syncthreads();
            }
        }
    }
    __syncthreads();

    int nsel=(int)selc; if(nsel>K_) nsel=K_;
    for(int k=t;k<nsel;k+=256){
        int idx = sel[k];
        int cls = idx / HW_;
        int sp  = idx - cls*HW_;
        int yi = sp>>7, xi = sp&(W_-1);
        float rr0 = reg[(b*2+0)*HW_+sp], rr1 = reg[(b*2+1)*HW_+sp];
        float w0 = wh[(b*2+0)*HW_+sp],  w1 = wh[(b*2+1)*HW_+sp];
        float xs = (float)xi + rr0, ys = (float)yi + rr1;
        float x1=xs-w0*0.5f, y1=ys-w1*0.5f, x2=xs+w0*0.5f, y2=ys+w1*0.5f;
        sbx[k][0]=x1; sbx[k][1]=y1; sbx[k][2]=x2; sbx[k][3]=y2;
        sa[k] = fmaxf(x2-x1,0.f)*fmaxf(y2-y1,0.f);
        ioui[k] = 0;
    }
    __syncthreads();
    int ng = (int)gcnt; if(ng>NGT_) ng=NGT_;
    for(int pi=t; pi<nsel*ng; pi+=256){
        int k = pi / ng, g = pi - k*ng;
        float x1=sbx[k][0], y1=sbx[k][1], x2=sbx[k][2], y2=sbx[k][3];
        float ix1=fmaxf(x1,gbox[g][0]), iy1=fmaxf(y1,gbox[g][1]);
        float ix2=fminf(x2,gbox[g][2]), iy2=fminf(y2,gbox[g][3]);
        float iw=fmaxf(ix2-ix1,0.f), ih=fmaxf(iy2-iy1,0.f);
        float inter=iw*ih;
        float uni = sa[k] + garea[g] - inter;
        float iou = inter / fmaxf(uni, 1e-7f);
        atomicMax(&ioui[k], __float_as_int(iou));
    }
    __syncthreads();
    for(int k=t;k<nsel;k+=256){
        float best = __int_as_float(ioui[k]);
        int gidx = b*CHW_ + sel[k];
        float v = hm[gidx];
        float p = 1.f/(1.f + __expf(-v));
        p = fminf(fmaxf(p, 1e-4f), 1.f - 1e-4f);
        float gt0 = hmt[gidx];
        float q0 = 1.f - gt0; float q02 = q0*q0;
        float neg0 = __logf(1.f - p) * p * p * q02 * q02;
        float gt1 = fminf(gt0 + 0.1f*best, 1.f);
        if(gt1 == 1.f){
            atomicAdd(&misc[0], 1);
            float op = 1.f - p;
            atomicAdd(&accum[1], (double)(__logf(p)*op*op));
            atomicAdd(&accum[2], (double)(-neg0));
        } else {
            float q1 = 1.f - gt1; float q12 = q1*q1;
            float neg1 = __logf(1.f - p) * p * p * q12 * q12;
            atomicAdd(&accum[2], (double)(neg1 - neg0));
        }
    }

    __threadfence();
    __syncthreads();
    if(t==0){
        unsigned d = atomicAdd(seldone, 1u);
        amlast = (d == (unsigned)(B_-1));
    }
    __syncthreads();
    if(amlast){
        __threadfence();
        float whn=0.f, offn=0.f, ms=0.f;
        for(int i=t;i<B_*MAXOBJS_;i+=256){
            int bb = i >> 7;
            float mk = (float)mask[i];
            int id = ind[i];
            float p0 = wh[(bb*2+0)*HW_+id], p1 = wh[(bb*2+1)*HW_+id];
            whn += mk*(fabsf(p0 - wht[2*i]) + fabsf(p1 - wht[2*i+1]));
            float q0 = reg[(bb*2+0)*HW_+id], q1 = reg[(bb*2+1)*HW_+id];
            offn += mk*(fabsf(q0 - regt[2*i]) + fabsf(q1 - regt[2*i+1]));
            ms += 2.f*mk;
        }
        r0s[t]=whn; r1s[t]=offn; r2s[t]=ms;
        __syncthreads();
        for(int st=128; st>0; st>>=1){
            if(t<st){ r0s[t]+=r0s[t+st]; r1s[t]+=r1s[t+st]; r2s[t]+=r2s[t+st]; }
            __syncthreads();
        }
        if(t==0){
            double nb  = __hip_atomic_load(&accum[0], __ATOMIC_RELAXED, __HIP_MEMORY_SCOPE_AGENT);
            double pos = __hip_atomic_load(&accum[1], __ATOMIC_RELAXED, __HIP_MEMORY_SCOPE_AGENT);
            double nd  = __hip_atomic_load(&accum[2], __ATOMIC_RELAXED, __HIP_MEMORY_SCOPE_AGENT);
            int np = __hip_atomic_load(&misc[0], __ATOMIC_RELAXED, __HIP_MEMORY_SCOPE_AGENT);
            double neg = nb + nd;
            float hm_loss = (np > 0) ? (float)(-(pos + neg)/(double)np) : (float)(-neg);
            float msum = r2s[0];
            float wh_loss  = r0s[0] / (msum + 1e-4f);
            float off_loss = r1s[0] / (msum + 1e-4f);
            out[0] = hm_loss + 0.1f*wh_loss + off_loss;
            out[1] = hm_loss; out[2] = wh_loss; out[3] = off_loss;
        }
    }
}

extern "C" void kernel_launch(void* const* d_in, const int* in_sizes, int n_in,
                              void* d_out, int out_size, void* d_ws, size_t ws_size,
                              hipStream_t stream){
    const float* hm   = (const float*)d_in[0];
    const float* wh   = (const float*)d_in[1];
    const float* reg  = (const float*)d_in[2];
    const float* hmt  = (const float*)d_in[3];
    const float* wht  = (const float*)d_in[4];
    const float* regt = (const float*)d_in[5];
    const int*   mask = (const int*)d_in[6];
    const int*   ind  = (const int*)d_in[7];
    const float* tbox = (const float*)d_in[8];
    const int*   tbid = (const int*)d_in[9];

    char* ws = (char*)d_ws;
    double*   accum   = (double*)ws;
    int*      misc    = (int*)(ws + OFF_MISC);
    unsigned* listcnt = (unsigned*)(ws + OFF_LISTCNT);
    unsigned* seldone = (unsigned*)(ws + OFF_SELDONE);
    unsigned* thrbin  = (unsigned*)(ws + OFF_THRB);
    unsigned* cntA    = (unsigned*)(ws + OFF_CNTA);
    unsigned* cntB    = (unsigned*)(ws + OFF_CNTB);
    unsigned* hist    = (unsigned*)(ws + OFF_HIST);
    float*    defv    = (float*)(ws + OFF_DEFV);
    int*      defi    = (int*)(ws + OFF_DEFI);
    float*    borv    = (float*)(ws + OFF_BORV);
    int*      bori    = (int*)(ws + OFF_BORI);
    int2*     list    = (int2*)(ws + OFF_LIST);

    size_t capB = 0;
    if(ws_size >= (size_t)OFF_LIST + CAP_REQ*(size_t)B_*8ull){
        capB = (ws_size - (size_t)OFF_LIST) / ((size_t)B_*8ull);
        if(capB > CAP_MAX) capB = CAP_MAX;
    }

    hipMemsetAsync(ws, 0, ZERO_BYTES, stream);
    k_main<<<B_*C_*2, 256, 0, stream>>>(hm, hmt, hist, accum, listcnt, list, (int)capB);
    k_thresh<<<B_, 256, 0, stream>>>(hist, thrbin);
    if(capB){
        k_scan<<<B_*64, 256, 0, stream>>>(list, listcnt, (int)capB, thrbin,
                                          cntA, cntB, defv, defi, borv, bori);
    } else {
        k_collect<<<TOT_/256, 256, 0, stream>>>(hm, thrbin, cntA, cntB,
                                                defv, defi, borv, bori);
    }
    k_select<<<B_, 256, 0, stream>>>(hm, hmt, wh, reg, tbox, tbid,
                                     wht, regt, mask, ind, cntA, cntB,
                                     defv, defi, borv, bori, accum, misc,
                                     seldone, (float*)d_out);
    (void)in_sizes; (void)n_in; (void)out_size;
}